// Round 4
// baseline (370.905 us; speedup 1.0000x reference)
//
#include <hip/hip_runtime.h>
#include <math.h>

#define B_SZ 2
#define LSEQ 1024
#define D_INP 1024
#define D_MODEL 2048
#define D_STATE 16
#define D_DISCR 128
#define MROWS (B_SZ * LSEQ)
#define NCH 16
#define CH 64

typedef __bf16 bf16x8 __attribute__((ext_vector_type(8)));
typedef float f32x4 __attribute__((ext_vector_type(4)));
typedef unsigned short ushort8 __attribute__((ext_vector_type(8)));

__device__ __forceinline__ float siluf(float x) { return x / (1.f + expf(-x)); }
__device__ __forceinline__ float softplusf(float x) {
    return fmaxf(x, 0.f) + log1pf(expf(-fabsf(x)));
}
__device__ __forceinline__ unsigned short f2b(float f) {
    unsigned u = __builtin_bit_cast(unsigned, f);
    u = u + 0x7fffu + ((u >> 16) & 1u);
    return (unsigned short)(u >> 16);
}
// async global->LDS, 16B per lane; LDS dest = wave-uniform base + lane*16
__device__ __forceinline__ void gl2lds16(const unsigned short* g, unsigned short* l) {
    __builtin_amdgcn_global_load_lds(
        (const __attribute__((address_space(1))) void*)g,
        (__attribute__((address_space(3))) void*)l, 16, 0, 0);
}

// ---------------------------------------------------------------------------
// one-shot cast of all fp32 inputs to bf16 (8 elems/thread)
__global__ __launch_bounds__(256) void cast_all(
    const float* __restrict__ seq, const float* __restrict__ w_in,
    const float* __restrict__ w_out, const float* __restrict__ w_B,
    const float* __restrict__ w_C, const float* __restrict__ w_D1,
    const float* __restrict__ w_D2,
    unsigned short* __restrict__ seq_b, unsigned short* __restrict__ win_b,
    unsigned short* __restrict__ wout_b, unsigned short* __restrict__ wbcd_b,
    unsigned short* __restrict__ wd2_b)
{
    int i = blockIdx.x * 256 + threadIdx.x;
    const float* src; unsigned short* dst; int off;
    if      (i < 262144)  { src = seq;  dst = seq_b;          off = i; }
    else if (i < 786432)  { src = w_in; dst = win_b;          off = i - 262144; }
    else if (i < 1048576) { src = w_out; dst = wout_b;        off = i - 786432; }
    else if (i < 1052672) { src = w_B;  dst = wbcd_b;         off = i - 1048576; }
    else if (i < 1056768) { src = w_C;  dst = wbcd_b + 32768; off = i - 1052672; }
    else if (i < 1089536) { src = w_D1; dst = wbcd_b + 65536; off = i - 1056768; }
    else if (i < 1122304) { src = w_D2; dst = wd2_b;          off = i - 1089536; }
    else return;
    const float4* p = (const float4*)(src + (size_t)off * 8);
    float4 a = p[0], b = p[1];
    ushort8 o = {f2b(a.x), f2b(a.y), f2b(a.z), f2b(a.w),
                 f2b(b.x), f2b(b.y), f2b(b.z), f2b(b.w)};
    *(ushort8*)(dst + (size_t)off * 8) = o;
}

// ---------------------------------------------------------------------------
// bf16 MFMA GEMM-NT with global_load_lds staging (m97 pattern).
// C[M,N] = A[M,K_total] @ B[N,K_total]^T ; this block does K chunk
// [z*K, z*K+K) and writes to Cbase + z*partStride.
// TN=128: 4 waves 2x2, 4x4 frags. TN=64: 4 waves stacked on rows, 2x4 frags.
// LDS: unpadded row-major [rows][32] bf16 (lane-contiguous, forced by
// global_load_lds wave-uniform-base semantics).
// epi: 0 = fp32 store; 2 = softplus(bias[col]+acc) fp32 store.
template <int TN>
__global__ __launch_bounds__(256) void gemm_lds(
    const unsigned short* __restrict__ A, int lda,
    const unsigned short* __restrict__ B, int ldb,
    float* __restrict__ Cbase, int ldc, size_t partStride,
    int N, int K, const float* __restrict__ bias, int epi)
{
    __shared__ unsigned short As[128 * 32];
    __shared__ unsigned short Bs[TN * 32];
    const int t = threadIdx.x;
    const int w = t >> 6, lane = t & 63;
    const int fr = lane & 15, fq = lane >> 4;
    const int row0 = blockIdx.y * 128, col0 = blockIdx.x * TN;
    const int kz = blockIdx.z * K;
    const int srow = lane >> 2, sq = lane & 3;   // 16 rows x 4 quads per wave-instr

    const unsigned short* ga0 = A + (size_t)(row0 + w * 16 + srow) * lda + kz + sq * 8;
    const unsigned short* ga1 = ga0 + (size_t)64 * lda;
    unsigned short* la0 = As + (w * 16) * 32;
    unsigned short* la1 = As + (64 + w * 16) * 32;
    const unsigned short* gb0 = B + (size_t)(col0 + w * 16 + srow) * ldb + kz + sq * 8;
    unsigned short* lb0 = Bs + (w * 16) * 32;
    const unsigned short* gb1 = gb0 + (size_t)64 * ldb;
    unsigned short* lb1 = Bs + ((TN == 128 ? 64 : 0) + w * 16) * 32;

    constexpr int NI = (TN == 128) ? 4 : 2;
    const int rbase = (TN == 128) ? (w >> 1) * 64 : w * 32;
    const int cbase = (TN == 128) ? (w & 1) * 64 : 0;

    f32x4 acc[NI][4];
#pragma unroll
    for (int i = 0; i < NI; i++)
#pragma unroll
        for (int j = 0; j < 4; j++) acc[i][j] = (f32x4){0.f, 0.f, 0.f, 0.f};

    for (int k0 = 0; k0 < K; k0 += 32) {
        __syncthreads();                     // previous frag reads done
        gl2lds16(ga0, la0);
        gl2lds16(ga1, la1);
        gl2lds16(gb0, lb0);
        if (TN == 128) gl2lds16(gb1, lb1);
        ga0 += 32; ga1 += 32; gb0 += 32; gb1 += 32;
        __syncthreads();                     // vmcnt(0) drain: LDS ready

        bf16x8 af[NI], bfr[4];
#pragma unroll
        for (int i = 0; i < NI; i++) {
            ushort8 u = *(const ushort8*)(As + (rbase + i * 16 + fr) * 32 + fq * 8);
            af[i] = __builtin_bit_cast(bf16x8, u);
        }
#pragma unroll
        for (int j = 0; j < 4; j++) {
            ushort8 u = *(const ushort8*)(Bs + (cbase + j * 16 + fr) * 32 + fq * 8);
            bfr[j] = __builtin_bit_cast(bf16x8, u);
        }
#pragma unroll
        for (int i = 0; i < NI; i++)
#pragma unroll
            for (int j = 0; j < 4; j++)
                acc[i][j] = __builtin_amdgcn_mfma_f32_16x16x32_bf16(
                    af[i], bfr[j], acc[i][j], 0, 0, 0);
    }

    float* C = Cbase + (size_t)blockIdx.z * partStride;
#pragma unroll
    for (int i = 0; i < NI; i++) {
#pragma unroll
        for (int j = 0; j < 4; j++) {
            int col = col0 + cbase + j * 16 + fr;
            if (col >= N) continue;
#pragma unroll
            for (int r = 0; r < 4; r++) {
                int row = row0 + rbase + i * 16 + fq * 4 + r;
                float v = acc[i][j][r];
                C[(size_t)row * ldc + col] = (epi == 2) ? softplusf(bias[col] + v) : v;
            }
        }
    }
}

// ---------------------------------------------------------------------------
// sum 8 split-K partials -> bcdB bf16 [2048,160] + fp32 B/C copy bc32 [2048,32]
__global__ __launch_bounds__(256) void bcd_reduce(
    const float* __restrict__ part, unsigned short* __restrict__ bcdB,
    float* __restrict__ bc32)
{
    int t = blockIdx.x * 256 + threadIdx.x;
    if (t >= 327680) return;
    float s = 0.f;
#pragma unroll
    for (int z = 0; z < 8; z++) s += part[(size_t)z * 327680 + t];
    bcdB[t] = f2b(s);
    int col = t % 160;
    if (col < 32) bc32[(size_t)(t / 160) * 32 + col] = s;
}

// ---------------------------------------------------------------------------
// depthwise causal conv1d (K=4) + bias + SiLU; fp32 + bf16 outputs
__global__ __launch_bounds__(256) void conv_silu(
    const float* __restrict__ ab,
    const float* __restrict__ cw, const float* __restrict__ cb,
    float* __restrict__ aConv, unsigned short* __restrict__ aConvB)
{
    int idx = blockIdx.x * 256 + threadIdx.x;
    int d = idx & (D_MODEL - 1);
    int bl = idx >> 11;
    int l = bl & (LSEQ - 1);
    float w0 = cw[d * 4 + 0], w1 = cw[d * 4 + 1], w2 = cw[d * 4 + 2], w3 = cw[d * 4 + 3];
    const float* col = ab + (size_t)bl * 4096 + d;
    float acc = cb[d];
    acc = fmaf(col[0], w3, acc);
    if (l >= 1) acc = fmaf(*(col - 4096), w2, acc);
    if (l >= 2) acc = fmaf(*(col - 2 * 4096), w1, acc);
    if (l >= 3) acc = fmaf(*(col - 3 * 4096), w0, acc);
    float s = siluf(acc);
    aConv[idx] = s;
    aConvB[idx] = f2b(s);
}

// ---------------------------------------------------------------------------
// Chunk-parallel scan (16 chunks x 64). bc32: [MROWS,32] = B|C fp32.
__global__ __launch_bounds__(256) void scan_phaseA(
    const float* __restrict__ delta, const float* __restrict__ aConv,
    const float* __restrict__ bc32, const float* __restrict__ A_param,
    float* __restrict__ hend, float* __restrict__ prod)
{
    int blk = blockIdx.x;
    int d = ((blk & 7) << 8) + threadIdx.x;
    int c = (blk >> 3) & 15;
    int b = blk >> 7;
    float expA[16], h[16], p[16];
#pragma unroll
    for (int s = 0; s < 16; s++) {
        expA[s] = expf(-A_param[d * 16 + s]);
        h[s] = 0.f; p[s] = 1.f;
    }
    int r0 = b * LSEQ + c * CH;
    const float* dp = delta + (size_t)r0 * D_MODEL + d;
    const float* ap = aConv + (size_t)r0 * D_MODEL + d;
    const float4* bp = (const float4*)(bc32 + (size_t)r0 * 32);
    for (int l = 0; l < CH; l++) {
        float dlt = *dp, av = *ap;
        float4 B0 = bp[0], B1 = bp[1], B2 = bp[2], B3 = bp[3];
        float Bv[16] = {B0.x, B0.y, B0.z, B0.w, B1.x, B1.y, B1.z, B1.w,
                        B2.x, B2.y, B2.z, B2.w, B3.x, B3.y, B3.z, B3.w};
        float x = dlt * av;
#pragma unroll
        for (int s = 0; s < 16; s++) {
            float Ab = expA[s] * dlt;
            h[s] = fmaf(Ab, h[s], Bv[s] * x);
            p[s] *= Ab;
        }
        dp += D_MODEL; ap += D_MODEL; bp += 8;
    }
    size_t base = ((size_t)(b * 16 + c) * 16 << 11) + d;
#pragma unroll
    for (int s = 0; s < 16; s++) {
        hend[base + ((size_t)s << 11)] = h[s];
        prod[base + ((size_t)s << 11)] = p[s];
    }
}

__global__ __launch_bounds__(256) void scan_phaseB(
    float* __restrict__ hend, const float* __restrict__ prod)
{
    int t = blockIdx.x * 256 + threadIdx.x;
    int d = t & 2047, s = (t >> 11) & 15, b = t >> 15;
    float h = 0.f;
    for (int c = 0; c < NCH; c++) {
        size_t idx = (((size_t)(b * 16 + c) * 16 + s) << 11) + d;
        float he = hend[idx], p = prod[idx];
        hend[idx] = h;
        h = fmaf(p, h, he);
    }
}

__global__ __launch_bounds__(256) void scan_phaseC(
    const float* __restrict__ delta, const float* __restrict__ aConv,
    const float* __restrict__ ab, const float* __restrict__ bc32,
    const float* __restrict__ A_param, const float* __restrict__ D_param,
    const float* __restrict__ hend, unsigned short* __restrict__ outB)
{
    int blk = blockIdx.x;
    int d = ((blk & 7) << 8) + threadIdx.x;
    int c = (blk >> 3) & 15;
    int b = blk >> 7;
    float expA[16], h[16];
    size_t base = ((size_t)(b * 16 + c) * 16 << 11) + d;
#pragma unroll
    for (int s = 0; s < 16; s++) {
        expA[s] = expf(-A_param[d * 16 + s]);
        h[s] = hend[base + ((size_t)s << 11)];
    }
    float Dp = D_param[d];
    int r0 = b * LSEQ + c * CH;
    const float* dp = delta + (size_t)r0 * D_MODEL + d;
    const float* ap = aConv + (size_t)r0 * D_MODEL + d;
    const float* gp = ab + (size_t)r0 * 4096 + D_MODEL + d;
    const float4* bp = (const float4*)(bc32 + (size_t)r0 * 32);
    unsigned short* op = outB + (size_t)r0 * D_MODEL + d;
    for (int l = 0; l < CH; l++) {
        float dlt = *dp, av = *ap, g = *gp;
        float4 B0 = bp[0], B1 = bp[1], B2 = bp[2], B3 = bp[3];
        float4 C0 = bp[4], C1 = bp[5], C2 = bp[6], C3 = bp[7];
        float Bv[16] = {B0.x, B0.y, B0.z, B0.w, B1.x, B1.y, B1.z, B1.w,
                        B2.x, B2.y, B2.z, B2.w, B3.x, B3.y, B3.z, B3.w};
        float Cv[16] = {C0.x, C0.y, C0.z, C0.w, C1.x, C1.y, C1.z, C1.w,
                        C2.x, C2.y, C2.z, C2.w, C3.x, C3.y, C3.z, C3.w};
        float x = dlt * av;
        float acc = 0.f;
#pragma unroll
        for (int s = 0; s < 16; s++) {
            float Ab = expA[s] * dlt;
            h[s] = fmaf(Ab, h[s], Bv[s] * x);
            acc = fmaf(h[s], Cv[s], acc);
        }
        *op = f2b((acc + Dp * av) * siluf(g));
        dp += D_MODEL; ap += D_MODEL; gp += 4096; bp += 8; op += D_MODEL;
    }
}

extern "C" void kernel_launch(void* const* d_in, const int* in_sizes, int n_in,
                              void* d_out, int out_size, void* d_ws, size_t ws_size,
                              hipStream_t stream) {
    const float* seq = (const float*)d_in[0];
    const float* w_in = (const float*)d_in[1];
    const float* w_out = (const float*)d_in[2];
    const float* w_B = (const float*)d_in[3];
    const float* w_C = (const float*)d_in[4];
    const float* w_D1 = (const float*)d_in[5];
    const float* w_D2 = (const float*)d_in[6];
    const float* conv_w = (const float*)d_in[7];
    const float* conv_b = (const float*)d_in[8];
    const float* A_param = (const float*)d_in[9];
    const float* D_param = (const float*)d_in[10];
    float* out = (float*)d_out;

    // fp32 region
    float* ab      = (float*)d_ws;                 // 2048*4096
    float* aConv32 = ab + (size_t)8388608;         // 2048*2048
    float* delta   = aConv32 + (size_t)4194304;    // 2048*2048
    float* bc32    = delta + (size_t)4194304;      // 2048*32
    float* hend    = bc32 + (size_t)65536;
    float* prod    = hend + (size_t)1048576;
    float* part    = prod + (size_t)1048576;       // 8 * 2048*160
    // bf16 region
    unsigned short* seq_b  = (unsigned short*)(part + 2621440);
    unsigned short* win_b  = seq_b + (size_t)2097152;
    unsigned short* wout_b = win_b + (size_t)4194304;
    unsigned short* wbcd_b = wout_b + (size_t)2097152;  // [160,2048]
    unsigned short* wd2_b  = wbcd_b + (size_t)327680;   // [2048,128]
    unsigned short* aConvB = wd2_b + (size_t)262144;    // [2048,2048]
    unsigned short* bcdB   = aConvB + (size_t)4194304;  // [2048,160]
    unsigned short* outB   = bcdB + (size_t)327680;     // [2048,2048]

    // 0) all casts in one dispatch
    cast_all<<<dim3(4384), 256, 0, stream>>>(seq, w_in, w_out, w_B, w_C, w_D1, w_D2,
                                             seq_b, win_b, wout_b, wbcd_b, wd2_b);
    // 1) ab = seq @ w_in^T  [2048 x 4096] K=1024
    gemm_lds<128><<<dim3(32, 16), 256, 0, stream>>>(seq_b, 1024, win_b, 1024,
                                                    ab, 4096, 0, 4096, 1024, nullptr, 0);
    // 2) conv + SiLU
    conv_silu<<<dim3(16384), 256, 0, stream>>>(ab, conv_w, conv_b, aConv32, aConvB);
    // 3) bcd split-K x8: partials [8][2048][160]
    gemm_lds<128><<<dim3(2, 16, 8), 256, 0, stream>>>(aConvB, 2048, wbcd_b, 2048,
                                                      part, 160, 327680, 160, 256,
                                                      nullptr, 0);
    bcd_reduce<<<dim3(1280), 256, 0, stream>>>(part, bcdB, bc32);
    // 4) delta = softplus(D + d1 @ wD2^T)  [2048 x 2048] K=128
    gemm_lds<128><<<dim3(16, 16), 256, 0, stream>>>(bcdB + 32, 160, wd2_b, 128,
                                                    delta, 2048, 0, 2048, 128,
                                                    D_param, 2);
    // 5) chunk-parallel scan
    scan_phaseA<<<dim3(256), 256, 0, stream>>>(delta, aConv32, bc32, A_param, hend, prod);
    scan_phaseB<<<dim3(256), 256, 0, stream>>>(hend, prod);
    scan_phaseC<<<dim3(256), 256, 0, stream>>>(delta, aConv32, ab, bc32, A_param,
                                               D_param, hend, outB);
    // 6) out = ssm_out @ w_out^T  [2048 x 1024] K=2048, 128x64 tiles (256 blocks)
    gemm_lds<64><<<dim3(16, 16), 256, 0, stream>>>(outB, 2048, wout_b, 2048,
                                                   out, 1024, 0, 1024, 2048,
                                                   nullptr, 0);
}

// Round 5
// 307.602 us; speedup vs baseline: 1.2058x; 1.2058x over previous
//
#include <hip/hip_runtime.h>
#include <math.h>

#define B_SZ 2
#define LSEQ 1024
#define D_INP 1024
#define D_MODEL 2048
#define D_STATE 16
#define D_DISCR 128
#define MROWS (B_SZ * LSEQ)
#define NCH 16
#define CH 64

typedef __bf16 bf16x8 __attribute__((ext_vector_type(8)));
typedef float f32x4 __attribute__((ext_vector_type(4)));
typedef unsigned short ushort8 __attribute__((ext_vector_type(8)));

__device__ __forceinline__ float siluf(float x) { return x / (1.f + expf(-x)); }
__device__ __forceinline__ float softplusf(float x) {
    return fmaxf(x, 0.f) + log1pf(expf(-fabsf(x)));
}
__device__ __forceinline__ unsigned short f2b(float f) {
    unsigned u = __builtin_bit_cast(unsigned, f);
    u = u + 0x7fffu + ((u >> 16) & 1u);
    return (unsigned short)(u >> 16);
}

// ---------------------------------------------------------------------------
// one-shot cast of all fp32 inputs to bf16 (8 elems/thread)
__global__ __launch_bounds__(256) void cast_all(
    const float* __restrict__ seq, const float* __restrict__ w_in,
    const float* __restrict__ w_out, const float* __restrict__ w_B,
    const float* __restrict__ w_C, const float* __restrict__ w_D1,
    const float* __restrict__ w_D2,
    unsigned short* __restrict__ seq_b, unsigned short* __restrict__ win_b,
    unsigned short* __restrict__ wout_b, unsigned short* __restrict__ wbcd_b,
    unsigned short* __restrict__ wd2_b)
{
    int i = blockIdx.x * 256 + threadIdx.x;
    const float* src; unsigned short* dst; int off;
    if      (i < 262144)  { src = seq;  dst = seq_b;          off = i; }
    else if (i < 786432)  { src = w_in; dst = win_b;          off = i - 262144; }
    else if (i < 1048576) { src = w_out; dst = wout_b;        off = i - 786432; }
    else if (i < 1052672) { src = w_B;  dst = wbcd_b;         off = i - 1048576; }
    else if (i < 1056768) { src = w_C;  dst = wbcd_b + 32768; off = i - 1052672; }
    else if (i < 1089536) { src = w_D1; dst = wbcd_b + 65536; off = i - 1056768; }
    else if (i < 1122304) { src = w_D2; dst = wd2_b;          off = i - 1089536; }
    else return;
    const float4* p = (const float4*)(src + (size_t)off * 8);
    float4 a = p[0], b = p[1];
    ushort8 o = {f2b(a.x), f2b(a.y), f2b(a.z), f2b(a.w),
                 f2b(b.x), f2b(b.y), f2b(b.z), f2b(b.w)};
    *(ushort8*)(dst + (size_t)off * 8) = o;
}

// ---------------------------------------------------------------------------
// bf16 MFMA GEMM-NT, double-buffered LDS + VGPR staging, 1 barrier/K-iter.
// C[M,N] = A[M,Kt] @ B[N,Kt]^T; block does K-chunk [z*K, z*K+K) ->
// Cbase + z*partStride. TN=128: 4 waves 2x2 (4x4 frags); TN=64: waves
// row-stacked (2x4 frags). B rows beyond N are read unguarded (must point
// into allocated workspace) — results masked at the store.
// epi: 0 = fp32 store; 2 = softplus(bias[col]+acc) fp32 store.
template <int TN>
__global__ __launch_bounds__(256) void gemm_db(
    const unsigned short* __restrict__ A, int lda,
    const unsigned short* __restrict__ B, int ldb,
    float* __restrict__ Cbase, int ldc, size_t partStride,
    int N, int K, const float* __restrict__ bias, int epi)
{
    __shared__ unsigned short As[2][128 * 32];
    __shared__ unsigned short Bs[2][TN * 32];
    const int t = threadIdx.x;
    const int w = t >> 6, lane = t & 63;
    const int fr = lane & 15, fq = lane >> 4;
    const int row0 = blockIdx.y * 128, col0 = blockIdx.x * TN;
    const int kz = blockIdx.z * K;
    const int sr = t >> 2, sq = t & 3;     // 64 rows x 4 k-quads per pass

    constexpr int NI = (TN == 128) ? 4 : 2;
    const int rbase = (TN == 128) ? (w >> 1) * 64 : w * 32;
    const int cbase = (TN == 128) ? (w & 1) * 64 : 0;

    const unsigned short* gA0 = A + (size_t)(row0 + sr) * lda + kz + sq * 8;
    const unsigned short* gA1 = gA0 + (size_t)64 * lda;
    const unsigned short* gB0 = B + (size_t)(col0 + sr) * ldb + kz + sq * 8;
    const unsigned short* gB1 = gB0 + (size_t)64 * ldb;

    f32x4 acc[NI][4];
#pragma unroll
    for (int i = 0; i < NI; i++)
#pragma unroll
        for (int j = 0; j < 4; j++) acc[i][j] = (f32x4){0.f, 0.f, 0.f, 0.f};

    // prologue: stage k0=0 into buffer 0
    ushort8 a0 = *(const ushort8*)gA0;
    ushort8 a1 = *(const ushort8*)gA1;
    ushort8 b0 = *(const ushort8*)gB0;
    ushort8 b1;
    if (TN == 128) b1 = *(const ushort8*)gB1;
    *(ushort8*)&As[0][sr * 32 + sq * 8] = a0;
    *(ushort8*)&As[0][(64 + sr) * 32 + sq * 8] = a1;
    *(ushort8*)&Bs[0][sr * 32 + sq * 8] = b0;
    if (TN == 128) *(ushort8*)&Bs[0][(64 + sr) * 32 + sq * 8] = b1;
    __syncthreads();

    int buf = 0;
    for (int k0 = 0; k0 < K; k0 += 32) {
        const bool more = (k0 + 32 < K);
        if (more) {                        // issue next-iter loads (in flight
            gA0 += 32; gA1 += 32;          //  during frag reads + MFMA below)
            gB0 += 32; gB1 += 32;
            a0 = *(const ushort8*)gA0;
            a1 = *(const ushort8*)gA1;
            b0 = *(const ushort8*)gB0;
            if (TN == 128) b1 = *(const ushort8*)gB1;
        }
        bf16x8 af[NI], bfr[4];
#pragma unroll
        for (int i = 0; i < NI; i++) {
            ushort8 u = *(const ushort8*)&As[buf][(rbase + i * 16 + fr) * 32 + fq * 8];
            af[i] = __builtin_bit_cast(bf16x8, u);
        }
#pragma unroll
        for (int j = 0; j < 4; j++) {
            ushort8 u = *(const ushort8*)&Bs[buf][(cbase + j * 16 + fr) * 32 + fq * 8];
            bfr[j] = __builtin_bit_cast(bf16x8, u);
        }
#pragma unroll
        for (int i = 0; i < NI; i++)
#pragma unroll
            for (int j = 0; j < 4; j++)
                acc[i][j] = __builtin_amdgcn_mfma_f32_16x16x32_bf16(
                    af[i], bfr[j], acc[i][j], 0, 0, 0);
        if (more) {
            int nb = buf ^ 1;              // vmcnt wait lands here, post-MFMA
            *(ushort8*)&As[nb][sr * 32 + sq * 8] = a0;
            *(ushort8*)&As[nb][(64 + sr) * 32 + sq * 8] = a1;
            *(ushort8*)&Bs[nb][sr * 32 + sq * 8] = b0;
            if (TN == 128) *(ushort8*)&Bs[nb][(64 + sr) * 32 + sq * 8] = b1;
            __syncthreads();
            buf = nb;
        }
    }

    float* C = Cbase + (size_t)blockIdx.z * partStride;
#pragma unroll
    for (int i = 0; i < NI; i++) {
#pragma unroll
        for (int j = 0; j < 4; j++) {
            int col = col0 + cbase + j * 16 + fr;
            if (col >= N) continue;
#pragma unroll
            for (int r = 0; r < 4; r++) {
                int row = row0 + rbase + i * 16 + fq * 4 + r;
                float v = acc[i][j][r];
                C[(size_t)row * ldc + col] = (epi == 2) ? softplusf(bias[col] + v) : v;
            }
        }
    }
}

// ---------------------------------------------------------------------------
// sum 8 split-K partials -> bcdB bf16 [2048,160] + fp32 B/C copy bc32 [2048,32]
__global__ __launch_bounds__(256) void bcd_reduce(
    const float* __restrict__ part, unsigned short* __restrict__ bcdB,
    float* __restrict__ bc32)
{
    int t = blockIdx.x * 256 + threadIdx.x;
    if (t >= 327680) return;
    float s = 0.f;
#pragma unroll
    for (int z = 0; z < 8; z++) s += part[(size_t)z * 327680 + t];
    bcdB[t] = f2b(s);
    int col = t % 160;
    if (col < 32) bc32[(size_t)(t / 160) * 32 + col] = s;
}

// ---------------------------------------------------------------------------
// depthwise causal conv1d (K=4) + bias + SiLU; fp32 + bf16 outputs
__global__ __launch_bounds__(256) void conv_silu(
    const float* __restrict__ ab,
    const float* __restrict__ cw, const float* __restrict__ cb,
    float* __restrict__ aConv, unsigned short* __restrict__ aConvB)
{
    int idx = blockIdx.x * 256 + threadIdx.x;
    int d = idx & (D_MODEL - 1);
    int bl = idx >> 11;
    int l = bl & (LSEQ - 1);
    float w0 = cw[d * 4 + 0], w1 = cw[d * 4 + 1], w2 = cw[d * 4 + 2], w3 = cw[d * 4 + 3];
    const float* col = ab + (size_t)bl * 4096 + d;
    float acc = cb[d];
    acc = fmaf(col[0], w3, acc);
    if (l >= 1) acc = fmaf(*(col - 4096), w2, acc);
    if (l >= 2) acc = fmaf(*(col - 2 * 4096), w1, acc);
    if (l >= 3) acc = fmaf(*(col - 3 * 4096), w0, acc);
    float s = siluf(acc);
    aConv[idx] = s;
    aConvB[idx] = f2b(s);
}

// ---------------------------------------------------------------------------
// Chunk-parallel scan (16 chunks x 64). bc32: [MROWS,32] = B|C fp32.
__global__ __launch_bounds__(256) void scan_phaseA(
    const float* __restrict__ delta, const float* __restrict__ aConv,
    const float* __restrict__ bc32, const float* __restrict__ A_param,
    float* __restrict__ hend, float* __restrict__ prod)
{
    int blk = blockIdx.x;
    int d = ((blk & 7) << 8) + threadIdx.x;
    int c = (blk >> 3) & 15;
    int b = blk >> 7;
    float expA[16], h[16], p[16];
#pragma unroll
    for (int s = 0; s < 16; s++) {
        expA[s] = expf(-A_param[d * 16 + s]);
        h[s] = 0.f; p[s] = 1.f;
    }
    int r0 = b * LSEQ + c * CH;
    const float* dp = delta + (size_t)r0 * D_MODEL + d;
    const float* ap = aConv + (size_t)r0 * D_MODEL + d;
    const float4* bp = (const float4*)(bc32 + (size_t)r0 * 32);
    for (int l = 0; l < CH; l++) {
        float dlt = *dp, av = *ap;
        float4 B0 = bp[0], B1 = bp[1], B2 = bp[2], B3 = bp[3];
        float Bv[16] = {B0.x, B0.y, B0.z, B0.w, B1.x, B1.y, B1.z, B1.w,
                        B2.x, B2.y, B2.z, B2.w, B3.x, B3.y, B3.z, B3.w};
        float x = dlt * av;
#pragma unroll
        for (int s = 0; s < 16; s++) {
            float Ab = expA[s] * dlt;
            h[s] = fmaf(Ab, h[s], Bv[s] * x);
            p[s] *= Ab;
        }
        dp += D_MODEL; ap += D_MODEL; bp += 8;
    }
    size_t base = ((size_t)(b * 16 + c) * 16 << 11) + d;
#pragma unroll
    for (int s = 0; s < 16; s++) {
        hend[base + ((size_t)s << 11)] = h[s];
        prod[base + ((size_t)s << 11)] = p[s];
    }
}

__global__ __launch_bounds__(256) void scan_phaseB(
    float* __restrict__ hend, const float* __restrict__ prod)
{
    int t = blockIdx.x * 256 + threadIdx.x;
    int d = t & 2047, s = (t >> 11) & 15, b = t >> 15;
    float h = 0.f;
    for (int c = 0; c < NCH; c++) {
        size_t idx = (((size_t)(b * 16 + c) * 16 + s) << 11) + d;
        float he = hend[idx], p = prod[idx];
        hend[idx] = h;
        h = fmaf(p, h, he);
    }
}

__global__ __launch_bounds__(256) void scan_phaseC(
    const float* __restrict__ delta, const float* __restrict__ aConv,
    const float* __restrict__ ab, const float* __restrict__ bc32,
    const float* __restrict__ A_param, const float* __restrict__ D_param,
    const float* __restrict__ hend, unsigned short* __restrict__ outB)
{
    int blk = blockIdx.x;
    int d = ((blk & 7) << 8) + threadIdx.x;
    int c = (blk >> 3) & 15;
    int b = blk >> 7;
    float expA[16], h[16];
    size_t base = ((size_t)(b * 16 + c) * 16 << 11) + d;
#pragma unroll
    for (int s = 0; s < 16; s++) {
        expA[s] = expf(-A_param[d * 16 + s]);
        h[s] = hend[base + ((size_t)s << 11)];
    }
    float Dp = D_param[d];
    int r0 = b * LSEQ + c * CH;
    const float* dp = delta + (size_t)r0 * D_MODEL + d;
    const float* ap = aConv + (size_t)r0 * D_MODEL + d;
    const float* gp = ab + (size_t)r0 * 4096 + D_MODEL + d;
    const float4* bp = (const float4*)(bc32 + (size_t)r0 * 32);
    unsigned short* op = outB + (size_t)r0 * D_MODEL + d;
    for (int l = 0; l < CH; l++) {
        float dlt = *dp, av = *ap, g = *gp;
        float4 B0 = bp[0], B1 = bp[1], B2 = bp[2], B3 = bp[3];
        float4 C0 = bp[4], C1 = bp[5], C2 = bp[6], C3 = bp[7];
        float Bv[16] = {B0.x, B0.y, B0.z, B0.w, B1.x, B1.y, B1.z, B1.w,
                        B2.x, B2.y, B2.z, B2.w, B3.x, B3.y, B3.z, B3.w};
        float Cv[16] = {C0.x, C0.y, C0.z, C0.w, C1.x, C1.y, C1.z, C1.w,
                        C2.x, C2.y, C2.z, C2.w, C3.x, C3.y, C3.z, C3.w};
        float x = dlt * av;
        float acc = 0.f;
#pragma unroll
        for (int s = 0; s < 16; s++) {
            float Ab = expA[s] * dlt;
            h[s] = fmaf(Ab, h[s], Bv[s] * x);
            acc = fmaf(h[s], Cv[s], acc);
        }
        *op = f2b((acc + Dp * av) * siluf(g));
        dp += D_MODEL; ap += D_MODEL; gp += 4096; bp += 8; op += D_MODEL;
    }
}

extern "C" void kernel_launch(void* const* d_in, const int* in_sizes, int n_in,
                              void* d_out, int out_size, void* d_ws, size_t ws_size,
                              hipStream_t stream) {
    const float* seq = (const float*)d_in[0];
    const float* w_in = (const float*)d_in[1];
    const float* w_out = (const float*)d_in[2];
    const float* w_B = (const float*)d_in[3];
    const float* w_C = (const float*)d_in[4];
    const float* w_D1 = (const float*)d_in[5];
    const float* w_D2 = (const float*)d_in[6];
    const float* conv_w = (const float*)d_in[7];
    const float* conv_b = (const float*)d_in[8];
    const float* A_param = (const float*)d_in[9];
    const float* D_param = (const float*)d_in[10];
    float* out = (float*)d_out;

    // fp32 region
    float* ab      = (float*)d_ws;                 // 2048*4096
    float* aConv32 = ab + (size_t)8388608;         // 2048*2048
    float* delta   = aConv32 + (size_t)4194304;    // 2048*2048
    float* bc32    = delta + (size_t)4194304;      // 2048*32
    float* hend    = bc32 + (size_t)65536;
    float* prod    = hend + (size_t)1048576;
    float* part    = prod + (size_t)1048576;       // 8 * 2048*160
    // bf16 region
    unsigned short* seq_b  = (unsigned short*)(part + 2621440);
    unsigned short* win_b  = seq_b + (size_t)2097152;
    unsigned short* wout_b = win_b + (size_t)4194304;
    unsigned short* wbcd_b = wout_b + (size_t)2097152;  // [160,2048]
    unsigned short* wd2_b  = wbcd_b + (size_t)327680;   // [2048,128]
    unsigned short* aConvB = wd2_b + (size_t)262144;    // [2048,2048]
    unsigned short* bcdB   = aConvB + (size_t)4194304;  // [2048,160]
    unsigned short* outB   = bcdB + (size_t)327680;     // [2048,2048]

    // 0) all casts in one dispatch
    cast_all<<<dim3(4384), 256, 0, stream>>>(seq, w_in, w_out, w_B, w_C, w_D1, w_D2,
                                             seq_b, win_b, wout_b, wbcd_b, wd2_b);
    // 1) ab = seq @ w_in^T  [2048 x 4096] K=1024
    gemm_db<128><<<dim3(32, 16), 256, 0, stream>>>(seq_b, 1024, win_b, 1024,
                                                   ab, 4096, 0, 4096, 1024, nullptr, 0);
    // 2) conv + SiLU
    conv_silu<<<dim3(16384), 256, 0, stream>>>(ab, conv_w, conv_b, aConv32, aConvB);
    // 3) bcd split-K x8: partials [8][2048][160] (cols 160..255 read OOB rows of
    //    wbcd_b into adjacent ws — safe, masked at store)
    gemm_db<128><<<dim3(2, 16, 8), 256, 0, stream>>>(aConvB, 2048, wbcd_b, 2048,
                                                     part, 160, 327680, 160, 256,
                                                     nullptr, 0);
    bcd_reduce<<<dim3(1280), 256, 0, stream>>>(part, bcdB, bc32);
    // 4) delta = softplus(D + d1 @ wD2^T)  [2048 x 2048] K=128
    gemm_db<128><<<dim3(16, 16), 256, 0, stream>>>(bcdB + 32, 160, wd2_b, 128,
                                                   delta, 2048, 0, 2048, 128,
                                                   D_param, 2);
    // 5) chunk-parallel scan
    scan_phaseA<<<dim3(256), 256, 0, stream>>>(delta, aConv32, bc32, A_param, hend, prod);
    scan_phaseB<<<dim3(256), 256, 0, stream>>>(hend, prod);
    scan_phaseC<<<dim3(256), 256, 0, stream>>>(delta, aConv32, ab, bc32, A_param,
                                               D_param, hend, outB);
    // 6) out = ssm_out @ w_out^T  [2048 x 1024] K=2048, 128x64 tiles (256 blocks)
    gemm_db<64><<<dim3(16, 16), 256, 0, stream>>>(outB, 2048, wout_b, 2048,
                                                  out, 1024, 0, 1024, 2048,
                                                  nullptr, 0);
}